// Round 5
// baseline (540.082 us; speedup 1.0000x reference)
//
#include <hip/hip_runtime.h>

// N=8192, DIN=DH=DOUT=64, SPARSITY=0.01 -> ~82 nnz/row (max ~122; CAP=256 = 19 sigma)
#define NN 8192
#define DD 64
#define CAP 256
#define CHUNKS 8  // (NN/4)/256

// Streaming scan with wave-ballot compaction. One 256-thread block per row.
// 8 unconditional float4 A-loads/thread, predicated lw loads, then per chunk:
// 4 ballots -> ONE LDS atomic per wave -> ranked direct global pair writes.
// No per-component exec branches, no LDS staging of pairs, no global atomics.
__global__ __launch_bounds__(256) void scan_kernel(
    const float* __restrict__ A, const float* __restrict__ lw,
    int2* __restrict__ pairs, int* __restrict__ cnt)
{
    __shared__ int scnt;
    const int tid  = threadIdx.x;
    const int lane = tid & 63;
    const int r    = blockIdx.x;

    if (tid == 0) scnt = 0;
    __syncthreads();

    const float4* A4 = (const float4*)(A + (size_t)r * NN);
    const float4* L4 = (const float4*)(lw + (size_t)r * NN);
    const int base = r * CAP;

    float4 a[CHUNKS];
    #pragma unroll
    for (int k = 0; k < CHUNKS; ++k) a[k] = A4[tid + 256 * k];

    bool nz[CHUNKS];
    #pragma unroll
    for (int k = 0; k < CHUNKS; ++k)
        nz[k] = (a[k].x != 0.f) || (a[k].y != 0.f) || (a[k].z != 0.f) || (a[k].w != 0.f);

    float4 l[CHUNKS];
    #pragma unroll
    for (int k = 0; k < CHUNKS; ++k)
        if (nz[k]) l[k] = L4[tid + 256 * k];   // exec-masked: ~4% of lanes

    const unsigned long long below = (1ull << lane) - 1ull;

    #pragma unroll
    for (int k = 0; k < CHUNKS; ++k) {
        const unsigned long long m0 = __ballot(a[k].x != 0.f);
        const unsigned long long m1 = __ballot(a[k].y != 0.f);
        const unsigned long long m2 = __ballot(a[k].z != 0.f);
        const unsigned long long m3 = __ballot(a[k].w != 0.f);
        const int c0 = __popcll(m0), c1 = __popcll(m1),
                  c2 = __popcll(m2), c3 = __popcll(m3);
        const int total = c0 + c1 + c2 + c3;     // wave-uniform
        if (total) {                             // uniform branch (~92% taken)
            int wbase;
            if (lane == 0) wbase = atomicAdd(&scnt, total);  // 1 atomic/wave/chunk
            wbase = __shfl(wbase, 0);
            const int cbase = 4 * (tid + 256 * k);
            // per-lane ranks within this chunk's 4 component masks
            if (a[k].x != 0.f) {
                int p = wbase + __popcll(m0 & below);
                if (p < CAP) pairs[base + p] = make_int2(cbase + 0, __float_as_int(l[k].x));
            }
            if (a[k].y != 0.f) {
                int p = wbase + c0 + __popcll(m1 & below);
                if (p < CAP) pairs[base + p] = make_int2(cbase + 1, __float_as_int(l[k].y));
            }
            if (a[k].z != 0.f) {
                int p = wbase + c0 + c1 + __popcll(m2 & below);
                if (p < CAP) pairs[base + p] = make_int2(cbase + 2, __float_as_int(l[k].z));
            }
            if (a[k].w != 0.f) {
                int p = wbase + c0 + c1 + c2 + __popcll(m3 & below);
                if (p < CAP) pairs[base + p] = make_int2(cbase + 3, __float_as_int(l[k].w));
            }
        }
    }
    __syncthreads();
    if (tid == 0) cnt[r] = (scnt < CAP) ? scnt : CAP;
}

// Layer pass (x3): 4 rows per 256-thread block, wave = row (unchanged from R4).
__global__ __launch_bounds__(256) void layer_kernel(
    const float* __restrict__ xin,
    const int2* __restrict__ pairs, const int* __restrict__ cnt,
    const float* __restrict__ W, const float* __restrict__ bias,
    float* __restrict__ xout)
{
    __shared__ float  WT[DD * 65];
    __shared__ int2   spairs[4][CAP];
    __shared__ float4 sagg[4][16];

    const int tid  = threadIdx.x;
    const int wave = tid >> 6;
    const int lane = tid & 63;
    const int grp  = lane >> 4;
    const int l16  = lane & 15;

    for (int i = tid; i < DD * DD; i += 256)
        WT[(i & 63) * 65 + (i >> 6)] = W[i];

    const int r  = blockIdx.x * 4 + wave;
    const int n  = cnt[r];
    const int nr = (n + 15) & ~15;
    const size_t base = (size_t)r * CAP;

    for (int j = lane; j < n; j += 64)      spairs[wave][j] = pairs[base + j];
    for (int j = n + lane; j < nr; j += 64) spairs[wave][j] = make_int2(0, 0);
    __syncthreads();

    const float4* x4 = (const float4*)xin;
    float4 agg = make_float4(0.f, 0.f, 0.f, 0.f);
    for (int j0 = grp * 4; j0 < nr; j0 += 16) {
        int2 cv[4];
        #pragma unroll
        for (int t = 0; t < 4; ++t) cv[t] = spairs[wave][j0 + t];
        float4 xv[4];
        #pragma unroll
        for (int t = 0; t < 4; ++t)
            xv[t] = x4[(size_t)cv[t].x * (DD / 4) + l16];  // 4 gathers in flight
        #pragma unroll
        for (int t = 0; t < 4; ++t) {
            const float v = __int_as_float(cv[t].y);
            agg.x += v * xv[t].x; agg.y += v * xv[t].y;
            agg.z += v * xv[t].z; agg.w += v * xv[t].w;
        }
    }
    agg.x += __shfl_xor(agg.x, 16); agg.y += __shfl_xor(agg.y, 16);
    agg.z += __shfl_xor(agg.z, 16); agg.w += __shfl_xor(agg.w, 16);
    agg.x += __shfl_xor(agg.x, 32); agg.y += __shfl_xor(agg.y, 32);
    agg.z += __shfl_xor(agg.z, 32); agg.w += __shfl_xor(agg.w, 32);
    if (grp == 0) sagg[wave][l16] = agg;
    __syncthreads();

    const float* sa = (const float*)&sagg[wave][0];
    float acc = bias[lane];
    #pragma unroll 16
    for (int k = 0; k < DD; ++k)
        acc += sa[k] * WT[k * 65 + lane];
    xout[(size_t)r * DD + lane] = acc;
}

extern "C" void kernel_launch(void* const* d_in, const int* in_sizes, int n_in,
                              void* d_out, int out_size, void* d_ws, size_t ws_size,
                              hipStream_t stream) {
    const float* x  = (const float*)d_in[0];
    const float* A  = (const float*)d_in[1];
    const float* lw = (const float*)d_in[2];
    const float* W0 = (const float*)d_in[3];
    const float* b0 = (const float*)d_in[4];
    const float* W1 = (const float*)d_in[5];
    const float* b1 = (const float*)d_in[6];
    const float* W2 = (const float*)d_in[7];
    const float* b2 = (const float*)d_in[8];
    float* out = (float*)d_out;

    char* ws = (char*)d_ws;
    int2*  pairs = (int2*)ws;  ws += (size_t)NN * CAP * sizeof(int2);  // 16 MB
    int*   cnt   = (int*)ws;   ws += (size_t)NN * sizeof(int);
    float* bufA  = (float*)ws; ws += (size_t)NN * DD * sizeof(float);
    float* bufB  = (float*)ws;

    scan_kernel<<<NN, 256, 0, stream>>>(A, lw, pairs, cnt);
    layer_kernel<<<NN / 4, 256, 0, stream>>>(x,    pairs, cnt, W0, b0, bufA);
    layer_kernel<<<NN / 4, 256, 0, stream>>>(bufA, pairs, cnt, W1, b1, bufB);
    layer_kernel<<<NN / 4, 256, 0, stream>>>(bufB, pairs, cnt, W2, b2, out);
}